// Round 2
// baseline (2715.470 us; speedup 1.0000x reference)
//
#include <hip/hip_runtime.h>
#include <cstddef>

#define EPS 1e-5f
#define NNODE 30000
#define NEDGE 360000
#define NFEAT 92
#define EF 41
#define D 64
#define LAY 3
#define FCW 128
#define NG 64

typedef unsigned short bf16;

__device__ __forceinline__ float b2f(bf16 u) { return __uint_as_float(((unsigned)u) << 16); }
__device__ __forceinline__ bf16 f2b(float f) {
    unsigned u = __float_as_uint(f);
    unsigned r = (u + 0x7FFFu + ((u >> 16) & 1u)) >> 16;
    return (bf16)r;
}
__device__ __forceinline__ float softplusf(float x) {
    return fmaxf(x, 0.0f) + log1pf(expf(-fabsf(x)));
}

// ---------------- embedding matmul: pre = X[N,92] @ W[92,64] + b, accumulate col stats
#define EMB_RPB 64
__global__ __launch_bounds__(256) void k_emb_mm(const float* __restrict__ X, const float* __restrict__ W,
                                                const float* __restrict__ bias, float* __restrict__ pre,
                                                float* __restrict__ stats, int N) {
    __shared__ float xs[EMB_RPB][NFEAT];   // 23.5 KB; row stride 368B = 16B aligned
    __shared__ float red[4][2][64];
    int tid = threadIdx.x;
    int lane = tid & 63, wid = tid >> 6;
    int r0 = blockIdx.x * EMB_RPB;
    float w[NFEAT];
#pragma unroll
    for (int k = 0; k < NFEAT; k++) w[k] = W[k * D + lane];
    float bcol = bias[lane];
    // float4 staging: 23 float4 per row
    for (int i = tid; i < EMB_RPB * (NFEAT / 4); i += 256) {
        int rr = i / (NFEAT / 4), kk = i - rr * (NFEAT / 4);
        int r = r0 + rr;
        float4 v = (r < N) ? ((const float4*)(X + (size_t)r * NFEAT))[kk] : make_float4(0, 0, 0, 0);
        *(float4*)&xs[rr][kk * 4] = v;
    }
    __syncthreads();
    float s0 = 0.f, s1 = 0.f;
    for (int rr = wid * 16; rr < wid * 16 + 16; rr++) {
        int r = r0 + rr;
        if (r >= N) break;
        float acc = bcol;
#pragma unroll
        for (int k4 = 0; k4 < NFEAT; k4 += 4) {
            float4 xv = *(const float4*)&xs[rr][k4];
            acc += xv.x * w[k4] + xv.y * w[k4 + 1] + xv.z * w[k4 + 2] + xv.w * w[k4 + 3];
        }
        pre[r * D + lane] = acc;
        s0 += acc; s1 += acc * acc;
    }
    red[wid][0][lane] = s0; red[wid][1][lane] = s1;
    __syncthreads();
    if (tid < 64) {
        float a = red[0][0][lane] + red[1][0][lane] + red[2][0][lane] + red[3][0][lane];
        float b = red[0][1][lane] + red[1][1][lane] + red[2][1][lane] + red[3][1][lane];
        atomicAdd(&stats[lane], a);
        atomicAdd(&stats[64 + lane], b);
    }
}

// ---------------- BN + SiLU elementwise (stats finalized inline)
__global__ void k_bnsilu(const float* __restrict__ pre, const float* __restrict__ stats,
                         const float* __restrict__ g, const float* __restrict__ beta,
                         float* __restrict__ h, int N, float invn) {
    int idx = blockIdx.x * blockDim.x + threadIdx.x;
    int total = N * D / 4;
    if (idx >= total) return;
    int c0 = (idx * 4) & 63;
    float4 p = ((const float4*)pre)[idx];
    float pv[4] = {p.x, p.y, p.z, p.w}, o[4];
#pragma unroll
    for (int t = 0; t < 4; t++) {
        int c = c0 + t;
        float m = stats[c] * invn;
        float v = stats[64 + c] * invn - m * m;
        float sc = g[c] * rsqrtf(fmaxf(v, 0.f) + EPS);
        float sh = beta[c] - m * sc;
        float y = sc * pv[t] + sh;
        o[t] = y / (1.f + expf(-y));
    }
    ((float4*)h)[idx] = make_float4(o[0], o[1], o[2], o[3]);
}

// ---------------- node projections: SRC[n]=[h@Wg[0:64] | h@Ws[0:64]], DST=[h@Wg[64:128] | h@Ws[64:128]]
#define NP_RPB 64
__global__ __launch_bounds__(256) void k_nodeproj(const float* __restrict__ h, const float* __restrict__ Wc,
                                                  bf16* __restrict__ SRC, bf16* __restrict__ DST, int N) {
    __shared__ float hs[NP_RPB][D];   // 16 KB
    int tid = threadIdx.x;
    int j = tid & 63;
    int mat = tid >> 6;          // 0: src-gate 1: src-scr 2: dst-gate 3: dst-scr
    int jj = mat & 1;
    int roff = (mat >> 1) * 64;
    const float* Wb = Wc + ((size_t)jj * 169 + roff) * 64 + j;
    float w[D];
#pragma unroll
    for (int k = 0; k < D; k++) w[k] = Wb[k * 64];
    int r0 = blockIdx.x * NP_RPB;
    for (int i = tid; i < NP_RPB * D / 4; i += 256) {
        int rr = i >> 4, kk = (i & 15);
        int r = r0 + rr;
        float4 v = (r < N) ? ((const float4*)(h + (size_t)r * D))[kk] : make_float4(0, 0, 0, 0);
        *(float4*)&hs[rr][kk * 4] = v;
    }
    __syncthreads();
    bf16* out = (mat < 2) ? SRC : DST;
    int coff = jj * 64 + j;
    int rmax = min(NP_RPB, N - r0);
    for (int rr = 0; rr < rmax; rr++) {
        float acc = 0.f;
#pragma unroll
        for (int k4 = 0; k4 < D; k4 += 4) {
            float4 xv = *(const float4*)&hs[rr][k4];
            acc += xv.x * w[k4] + xv.y * w[k4 + 1] + xv.z * w[k4 + 2] + xv.w * w[k4 + 3];
        }
        out[(size_t)(r0 + rr) * 128 + coff] = f2b(acc);
    }
}

// ---------------- edge pass. MODE: 0 stats+store, 1 load+apply, 2 stats only, 3 recompute+apply
template <int MODE>
__global__ __launch_bounds__(256) void k_edge(const int* __restrict__ src, const int* __restrict__ dst,
                                              const float* __restrict__ ef, const float* __restrict__ Wc,
                                              const bf16* __restrict__ SRC, const bf16* __restrict__ DST,
                                              bf16* __restrict__ PRE, float* __restrict__ stats,
                                              const float* __restrict__ gg, const float* __restrict__ gb,
                                              const float* __restrict__ sg, const float* __restrict__ sb,
                                              float* __restrict__ upd, int E, int N) {
    int tid = threadIdx.x, lane = tid & 63, wid = tid >> 6;
    if (MODE == 0 || MODE == 2) {    // fuse: zero upd for the subsequent apply pass
        int gsz = gridDim.x * 256;
        for (int i = blockIdx.x * 256 + tid; i < N * D; i += gsz) upd[i] = 0.f;
    }
    float wg[EF], wsc[EF];
    if (MODE != 1) {
#pragma unroll
        for (int k = 0; k < EF; k++) {
            wg[k] = Wc[(128 + k) * 64 + lane];
            wsc[k] = Wc[(169 + 128 + k) * 64 + lane];
        }
    }
    float scg = 0, shg = 0, scs = 0, shs = 0;
    if (MODE == 1 || MODE == 3) {
        float invE = 1.0f / (float)E;
        float m = stats[lane] * invE;
        float v = stats[64 + lane] * invE - m * m;
        scg = gg[lane] * rsqrtf(fmaxf(v, 0.f) + EPS);
        shg = gb[lane] - m * scg;
        m = stats[128 + lane] * invE;
        v = stats[192 + lane] * invE - m * m;
        scs = sg[lane] * rsqrtf(fmaxf(v, 0.f) + EPS);
        shs = sb[lane] - m * scs;
    }
    __shared__ float erow[4][44];
    __shared__ float red[4][4][64];
    float a0 = 0, a1 = 0, a2 = 0, a3 = 0;
    int gw = blockIdx.x * 4 + wid, nw = gridDim.x * 4;
    for (int e = gw; e < E; e += nw) {
        int sN = src[e], dN = dst[e];
        float pg, ps;
        if (MODE != 1) {
            if (lane < EF) erow[wid][lane] = ef[(size_t)e * EF + lane];
            __builtin_amdgcn_wave_barrier();   // same-wave LDS RAW; compiler inserts waitcnt
            pg = b2f(SRC[(size_t)sN * 128 + lane]) + b2f(DST[(size_t)dN * 128 + lane]);
            ps = b2f(SRC[(size_t)sN * 128 + 64 + lane]) + b2f(DST[(size_t)dN * 128 + 64 + lane]);
#pragma unroll
            for (int k4 = 0; k4 < 40; k4 += 4) {
                float4 ev = *(const float4*)&erow[wid][k4];
                pg += ev.x * wg[k4] + ev.y * wg[k4 + 1] + ev.z * wg[k4 + 2] + ev.w * wg[k4 + 3];
                ps += ev.x * wsc[k4] + ev.y * wsc[k4 + 1] + ev.z * wsc[k4 + 2] + ev.w * wsc[k4 + 3];
            }
            {
                float ev = erow[wid][40];
                pg += ev * wg[40]; ps += ev * wsc[40];
            }
            bf16 gbit = f2b(pg), sbit = f2b(ps);
            pg = b2f(gbit); ps = b2f(sbit);   // keep stats consistent with stored precision
            if (MODE == 0) {
                PRE[(size_t)e * 128 + lane] = gbit;
                PRE[(size_t)e * 128 + 64 + lane] = sbit;
            }
            if (MODE == 0 || MODE == 2) { a0 += pg; a1 += pg * pg; a2 += ps; a3 += ps * ps; }
        } else {
            pg = b2f(PRE[(size_t)e * 128 + lane]);
            ps = b2f(PRE[(size_t)e * 128 + 64 + lane]);
        }
        if (MODE == 1 || MODE == 3) {
            float yg = scg * pg + shg;
            float ys = scs * ps + shs;
            float gate = 1.f / (1.f + expf(-yg));
            float scr = softplusf(ys);
            atomicAdd(&upd[(size_t)dN * D + lane], gate * scr);
        }
    }
    if (MODE == 0 || MODE == 2) {
        red[wid][0][lane] = a0; red[wid][1][lane] = a1; red[wid][2][lane] = a2; red[wid][3][lane] = a3;
        __syncthreads();
        if (tid < 64) {
#pragma unroll
            for (int t = 0; t < 4; t++) {
                float v = red[0][t][lane] + red[1][t][lane] + red[2][t][lane] + red[3][t][lane];
                atomicAdd(&stats[t * 64 + lane], v);
            }
        }
    }
}

// ---------------- column stats of upd
__global__ __launch_bounds__(256) void k_colstats(const float* __restrict__ x, float* __restrict__ stats, int N) {
    int tid = threadIdx.x, lane = tid & 63, wid = tid >> 6;
    __shared__ float red[4][2][64];
    float s = 0, q = 0;
    int gw = blockIdx.x * 4 + wid, nw = gridDim.x * 4;
    for (int r = gw; r < N; r += nw) {
        float v = x[(size_t)r * D + lane];
        s += v; q += v * v;
    }
    red[wid][0][lane] = s; red[wid][1][lane] = q;
    __syncthreads();
    if (tid < 64) {
        float a = red[0][0][lane] + red[1][0][lane] + red[2][0][lane] + red[3][0][lane];
        float b = red[0][1][lane] + red[1][1][lane] + red[2][1][lane] + red[3][1][lane];
        atomicAdd(&stats[lane], a);
        atomicAdd(&stats[64 + lane], b);
    }
}

// ---------------- h = softplus(BN(upd) + h)
__global__ void k_updapply(const float* __restrict__ upd, const float* __restrict__ stats,
                           const float* __restrict__ g, const float* __restrict__ beta,
                           float* __restrict__ h, int N, float invn) {
    int idx = blockIdx.x * blockDim.x + threadIdx.x;
    int total = N * D / 4;
    if (idx >= total) return;
    int c0 = (idx * 4) & 63;
    float4 u = ((const float4*)upd)[idx];
    float4 hh = ((const float4*)h)[idx];
    float uv[4] = {u.x, u.y, u.z, u.w}, hv[4] = {hh.x, hh.y, hh.z, hh.w}, o[4];
#pragma unroll
    for (int t = 0; t < 4; t++) {
        int c = c0 + t;
        float m = stats[c] * invn, v = stats[64 + c] * invn - m * m;
        float sc = g[c] * rsqrtf(fmaxf(v, 0.f) + EPS);
        float sh = beta[c] - m * sc;
        o[t] = softplusf(sc * uv[t] + sh + hv[t]);
    }
    ((float4*)h)[idx] = make_float4(o[0], o[1], o[2], o[3]);
}

// ---------------- segment-sum pool + counts
__global__ __launch_bounds__(256) void k_pool(const float* __restrict__ h, const int* __restrict__ batch,
                                              float* __restrict__ pool, float* __restrict__ cnt, int N) {
    int tid = threadIdx.x, lane = tid & 63, wid = tid >> 6;
    int gw = blockIdx.x * 4 + wid, nw = gridDim.x * 4;
    for (int r = gw; r < N; r += nw) {
        int b = batch[r];
        atomicAdd(&pool[(size_t)b * D + lane], h[(size_t)r * D + lane]);
        if (lane == 0) atomicAdd(&cnt[b], 1.0f);
    }
}

// ---------------- fc: Y[g][j] = vt[g] . fcW[:,j] + fcb[j]; accumulate col stats
__global__ __launch_bounds__(128) void k_fc(const float* __restrict__ pool, const float* __restrict__ cnt,
                                            const float* __restrict__ fcW, const float* __restrict__ fcb,
                                            float* __restrict__ Y, float* __restrict__ ystats) {
    int g = blockIdx.x;
    int j = threadIdx.x;
    __shared__ float vt[FCW];
    {
        float s, c;
        if (j < 64) { s = pool[(size_t)g * D + j]; c = cnt[g]; }
        else { s = pool[4096 + (size_t)g * D + (j - 64)]; c = cnt[64 + g]; }
        vt[j] = s / fmaxf(c, 1.0f);
    }
    __syncthreads();
    float acc = fcb[j];
#pragma unroll
    for (int k4 = 0; k4 < FCW; k4 += 4) {
        float4 v = *(const float4*)&vt[k4];
        acc += v.x * fcW[(k4 + 0) * FCW + j] + v.y * fcW[(k4 + 1) * FCW + j] +
               v.z * fcW[(k4 + 2) * FCW + j] + v.w * fcW[(k4 + 3) * FCW + j];
    }
    Y[(size_t)g * FCW + j] = acc;
    atomicAdd(&ystats[j], acc);
    atomicAdd(&ystats[128 + j], acc * acc);
}

// ---------------- head: BN over 64 rows + SiLU + pred matvec → out[64] f32
__global__ __launch_bounds__(128) void k_head(const float* __restrict__ Y, const float* __restrict__ ystats,
                                              const float* __restrict__ fg, const float* __restrict__ fb,
                                              const float* __restrict__ pW, const float* __restrict__ pb,
                                              float* __restrict__ out) {
    int j = threadIdx.x;
    __shared__ float ys[NG][FCW + 1];
    __shared__ float pw[FCW];
    float invn = 1.0f / (float)NG;
    float m = ystats[j] * invn, v = ystats[128 + j] * invn - m * m;
    float sc = fg[j] * rsqrtf(fmaxf(v, 0.f) + EPS);
    float sh = fb[j] - m * sc;
    for (int g = 0; g < NG; g++) {
        float y = sc * Y[(size_t)g * FCW + j] + sh;
        ys[g][j] = y / (1.f + expf(-y));
    }
    pw[j] = pW[j];
    __syncthreads();
    if (j < NG) {
        float acc = pb[0];
        for (int k = 0; k < FCW; k++) acc += ys[j][k] * pw[k];
        out[j] = acc;
    }
}

// ---------------- workspace layout (bytes)
static const size_t OFF_EMBSTATS = 0;          // [2][128] f32
static const size_t OFF_EDGESTATS = 1024;      // [6][256] f32
static const size_t OFF_UPDSTATS = 7168;       // [6][128] f32
static const size_t OFF_POOL = 10240;          // [2][4096] f32
static const size_t OFF_CNT = 43008;           // [2][64] f32
static const size_t OFF_YSTATS = 43520;        // [256] f32
static const size_t STATS_BYTES = 44544;
static const size_t OFF_H = 65536;                         // 30000*64*4
static const size_t OFF_PRE = OFF_H + 7680000;             // emb preact f32
static const size_t OFF_UPD = OFF_PRE + 7680000;           // f32
static const size_t OFF_SRCTAB = OFF_UPD + 7680000;        // bf16 [30000][128]
static const size_t OFF_DSTTAB = OFF_SRCTAB + 7680000;
static const size_t OFF_Y = OFF_DSTTAB + 7680000;          // [64][128] f32
static const size_t OFF_EPRE = OFF_Y + 32768;              // bf16 [360000][128]
static const size_t NEED_STORE = OFF_EPRE + (size_t)NEDGE * 128 * 2;

extern "C" void kernel_launch(void* const* d_in, const int* in_sizes, int n_in,
                              void* d_out, int out_size, void* d_ws, size_t ws_size,
                              hipStream_t stream) {
    char* ws = (char*)d_ws;
    hipMemsetAsync(d_ws, 0, STATS_BYTES, stream);
    bool store = (ws_size >= NEED_STORE);

    float* h = (float*)(ws + OFF_H);
    float* pre = (float*)(ws + OFF_PRE);
    float* upd = (float*)(ws + OFF_UPD);
    bf16* SRCT = (bf16*)(ws + OFF_SRCTAB);
    bf16* DSTT = (bf16*)(ws + OFF_DSTTAB);
    bf16* EPRE = (bf16*)(ws + OFF_EPRE);

    for (int br = 0; br < 2; br++) {
        const float* vf = (const float*)d_in[br ? 2 : 0];
        const float* ef = (const float*)d_in[br ? 3 : 1];
        const int* srci = (const int*)d_in[br ? 7 : 4];
        const int* dsti = (const int*)d_in[br ? 8 : 5];
        const int* bat = (const int*)d_in[br ? 9 : 6];
        const float* embW = (const float*)d_in[br ? 14 : 10];
        const float* embB = (const float*)d_in[br ? 15 : 11];
        const float* embG = (const float*)d_in[br ? 16 : 12];
        const float* embBe = (const float*)d_in[br ? 17 : 13];
        const float* convW = (const float*)d_in[br ? 24 : 18];
        const float* convG = (const float*)d_in[br ? 26 : 20];
        const float* convBe = (const float*)d_in[br ? 27 : 21];
        const float* convNG = (const float*)d_in[br ? 28 : 22];
        const float* convNB = (const float*)d_in[br ? 29 : 23];

        float* embstats = (float*)(ws + OFF_EMBSTATS) + br * 128;
        float* poolp = (float*)(ws + OFF_POOL) + br * 4096;
        float* cntp = (float*)(ws + OFF_CNT) + br * 64;

        k_emb_mm<<<(NNODE + EMB_RPB - 1) / EMB_RPB, 256, 0, stream>>>(vf, embW, embB, pre, embstats, NNODE);
        k_bnsilu<<<NNODE * D / 4 / 256, 256, 0, stream>>>(pre, embstats, embG, embBe, h, NNODE, 1.0f / NNODE);

        for (int i = 0; i < LAY; i++) {
            const float* Wc = convW + (size_t)i * 2 * 169 * 64;
            float* estats = (float*)(ws + OFF_EDGESTATS) + (br * 3 + i) * 256;
            float* ustats = (float*)(ws + OFF_UPDSTATS) + (br * 3 + i) * 128;
            const float* gg = convG + (i * 2 + 0) * 64;
            const float* gb = convBe + (i * 2 + 0) * 64;
            const float* sg = convG + (i * 2 + 1) * 64;
            const float* sb = convBe + (i * 2 + 1) * 64;

            k_nodeproj<<<(NNODE + NP_RPB - 1) / NP_RPB, 256, 0, stream>>>(h, Wc, SRCT, DSTT, NNODE);
            if (store) {
                k_edge<0><<<768, 256, 0, stream>>>(srci, dsti, ef, Wc, SRCT, DSTT, EPRE, estats, gg, gb, sg, sb, upd, NEDGE, NNODE);
                k_edge<1><<<768, 256, 0, stream>>>(srci, dsti, ef, Wc, SRCT, DSTT, EPRE, estats, gg, gb, sg, sb, upd, NEDGE, NNODE);
            } else {
                k_edge<2><<<768, 256, 0, stream>>>(srci, dsti, ef, Wc, SRCT, DSTT, EPRE, estats, gg, gb, sg, sb, upd, NEDGE, NNODE);
                k_edge<3><<<768, 256, 0, stream>>>(srci, dsti, ef, Wc, SRCT, DSTT, EPRE, estats, gg, gb, sg, sb, upd, NEDGE, NNODE);
            }
            k_colstats<<<256, 256, 0, stream>>>(upd, ustats, NNODE);
            k_updapply<<<NNODE * D / 4 / 256, 256, 0, stream>>>(upd, ustats, convNG + i * 64, convNB + i * 64, h, NNODE, 1.0f / NNODE);
        }
        k_pool<<<256, 256, 0, stream>>>(h, bat, poolp, cntp, NNODE);
    }

    float* poolall = (float*)(ws + OFF_POOL);
    float* cntall = (float*)(ws + OFF_CNT);
    float* Y = (float*)(ws + OFF_Y);
    float* ystats = (float*)(ws + OFF_YSTATS);
    k_fc<<<64, 128, 0, stream>>>(poolall, cntall, (const float*)d_in[30], (const float*)d_in[31], Y, ystats);
    k_head<<<1, 128, 0, stream>>>(Y, ystats, (const float*)d_in[32], (const float*)d_in[33],
                                  (const float*)d_in[34], (const float*)d_in[35], (float*)d_out);
}

// Round 3
// 2160.253 us; speedup vs baseline: 1.2570x; 1.2570x over previous
//
#include <hip/hip_runtime.h>
#include <cstddef>

#define EPS 1e-5f
#define NNODE 30000
#define NEDGE 360000
#define NFEAT 92
#define EF 41
#define D 64
#define LAY 3
#define FCW 128
#define NG 64

typedef unsigned short bf16;

__device__ __forceinline__ float b2f(bf16 u) { return __uint_as_float(((unsigned)u) << 16); }
__device__ __forceinline__ bf16 f2b(float f) {
    unsigned u = __float_as_uint(f);
    unsigned r = (u + 0x7FFFu + ((u >> 16) & 1u)) >> 16;
    return (bf16)r;
}
__device__ __forceinline__ float softplusf(float x) {
    return fmaxf(x, 0.0f) + log1pf(expf(-fabsf(x)));
}

// ---------------- embedding matmul: pre = X[N,92] @ W[92,64] + b, accumulate col stats
#define EMB_RPB 64
__global__ __launch_bounds__(256) void k_emb_mm(const float* __restrict__ X, const float* __restrict__ W,
                                                const float* __restrict__ bias, float* __restrict__ pre,
                                                float* __restrict__ stats, int N) {
    __shared__ float xs[EMB_RPB][NFEAT];   // 23.5 KB; row stride 368B = 16B aligned
    __shared__ float red[4][2][64];
    int tid = threadIdx.x;
    int lane = tid & 63, wid = tid >> 6;
    int r0 = blockIdx.x * EMB_RPB;
    float w[NFEAT];
#pragma unroll
    for (int k = 0; k < NFEAT; k++) w[k] = W[k * D + lane];
    float bcol = bias[lane];
    for (int i = tid; i < EMB_RPB * (NFEAT / 4); i += 256) {
        int rr = i / (NFEAT / 4), kk = i - rr * (NFEAT / 4);
        int r = r0 + rr;
        float4 v = (r < N) ? ((const float4*)(X + (size_t)r * NFEAT))[kk] : make_float4(0, 0, 0, 0);
        *(float4*)&xs[rr][kk * 4] = v;
    }
    __syncthreads();
    float s0 = 0.f, s1 = 0.f;
    for (int rr = wid * 16; rr < wid * 16 + 16; rr++) {
        int r = r0 + rr;
        if (r >= N) break;
        float acc = bcol;
#pragma unroll
        for (int k4 = 0; k4 < NFEAT; k4 += 4) {
            float4 xv = *(const float4*)&xs[rr][k4];
            acc += xv.x * w[k4] + xv.y * w[k4 + 1] + xv.z * w[k4 + 2] + xv.w * w[k4 + 3];
        }
        pre[r * D + lane] = acc;
        s0 += acc; s1 += acc * acc;
    }
    red[wid][0][lane] = s0; red[wid][1][lane] = s1;
    __syncthreads();
    if (tid < 64) {
        float a = red[0][0][lane] + red[1][0][lane] + red[2][0][lane] + red[3][0][lane];
        float b = red[0][1][lane] + red[1][1][lane] + red[2][1][lane] + red[3][1][lane];
        atomicAdd(&stats[lane], a);
        atomicAdd(&stats[64 + lane], b);
    }
}

// ---------------- BN + SiLU elementwise (stats finalized inline)
__global__ void k_bnsilu(const float* __restrict__ pre, const float* __restrict__ stats,
                         const float* __restrict__ g, const float* __restrict__ beta,
                         float* __restrict__ h, int N, float invn) {
    int idx = blockIdx.x * blockDim.x + threadIdx.x;
    int total = N * D / 4;
    if (idx >= total) return;
    int c0 = (idx * 4) & 63;
    float4 p = ((const float4*)pre)[idx];
    float pv[4] = {p.x, p.y, p.z, p.w}, o[4];
#pragma unroll
    for (int t = 0; t < 4; t++) {
        int c = c0 + t;
        float m = stats[c] * invn;
        float v = stats[64 + c] * invn - m * m;
        float sc = g[c] * rsqrtf(fmaxf(v, 0.f) + EPS);
        float sh = beta[c] - m * sc;
        float y = sc * pv[t] + sh;
        o[t] = y / (1.f + expf(-y));
    }
    ((float4*)h)[idx] = make_float4(o[0], o[1], o[2], o[3]);
}

// ---------------- node projections: SRC[n]=[h@Wg[0:64] | h@Ws[0:64]], DST=[h@Wg[64:128] | h@Ws[64:128]]
#define NP_RPB 64
__global__ __launch_bounds__(256) void k_nodeproj(const float* __restrict__ h, const float* __restrict__ Wc,
                                                  bf16* __restrict__ SRC, bf16* __restrict__ DST, int N) {
    __shared__ float hs[NP_RPB][D];   // 16 KB
    int tid = threadIdx.x;
    int j = tid & 63;
    int mat = tid >> 6;          // 0: src-gate 1: src-scr 2: dst-gate 3: dst-scr
    int jj = mat & 1;
    int roff = (mat >> 1) * 64;
    const float* Wb = Wc + ((size_t)jj * 169 + roff) * 64 + j;
    float w[D];
#pragma unroll
    for (int k = 0; k < D; k++) w[k] = Wb[k * 64];
    int r0 = blockIdx.x * NP_RPB;
    for (int i = tid; i < NP_RPB * D / 4; i += 256) {
        int rr = i >> 4, kk = (i & 15);
        int r = r0 + rr;
        float4 v = (r < N) ? ((const float4*)(h + (size_t)r * D))[kk] : make_float4(0, 0, 0, 0);
        *(float4*)&hs[rr][kk * 4] = v;
    }
    __syncthreads();
    bf16* out = (mat < 2) ? SRC : DST;
    int coff = jj * 64 + j;
    int rmax = min(NP_RPB, N - r0);
    for (int rr = 0; rr < rmax; rr++) {
        float acc = 0.f;
#pragma unroll
        for (int k4 = 0; k4 < D; k4 += 4) {
            float4 xv = *(const float4*)&hs[rr][k4];
            acc += xv.x * w[k4] + xv.y * w[k4 + 1] + xv.z * w[k4 + 2] + xv.w * w[k4 + 3];
        }
        out[(size_t)(r0 + rr) * 128 + coff] = f2b(acc);
    }
}

// ---------------- edge pass. MODE: 0 stats+store, 1 load+apply, 2 stats only, 3 recompute+apply
template <int MODE>
__global__ __launch_bounds__(256) void k_edge(const int* __restrict__ src, const int* __restrict__ dst,
                                              const float* __restrict__ ef, const float* __restrict__ Wc,
                                              const bf16* __restrict__ SRC, const bf16* __restrict__ DST,
                                              bf16* __restrict__ PRE, float* __restrict__ stats,
                                              const float* __restrict__ gg, const float* __restrict__ gb,
                                              const float* __restrict__ sg, const float* __restrict__ sb,
                                              float* __restrict__ upd, int E, int N) {
    int tid = threadIdx.x, lane = tid & 63, wid = tid >> 6;
    if (MODE == 0 || MODE == 2) {    // fuse: zero upd for the subsequent apply pass
        int gsz = gridDim.x * 256;
        for (int i = blockIdx.x * 256 + tid; i < N * D; i += gsz) upd[i] = 0.f;
    }
    float wg[EF], wsc[EF];
    if (MODE != 1) {
#pragma unroll
        for (int k = 0; k < EF; k++) {
            wg[k] = Wc[(128 + k) * 64 + lane];
            wsc[k] = Wc[(169 + 128 + k) * 64 + lane];
        }
    }
    float scg = 0, shg = 0, scs = 0, shs = 0;
    if (MODE == 1 || MODE == 3) {
        float invE = 1.0f / (float)E;
        float m = stats[lane] * invE;
        float v = stats[64 + lane] * invE - m * m;
        scg = gg[lane] * rsqrtf(fmaxf(v, 0.f) + EPS);
        shg = gb[lane] - m * scg;
        m = stats[128 + lane] * invE;
        v = stats[192 + lane] * invE - m * m;
        scs = sg[lane] * rsqrtf(fmaxf(v, 0.f) + EPS);
        shs = sb[lane] - m * scs;
    }
    __shared__ float erow[4][44];
    __shared__ float red[4][4][64];
    float a0 = 0, a1 = 0, a2 = 0, a3 = 0;
    int gw = blockIdx.x * 4 + wid, nw = gridDim.x * 4;
    for (int e = gw; e < E; e += nw) {
        int sN = src[e], dN = dst[e];
        float pg, ps;
        if (MODE != 1) {
            if (lane < EF) erow[wid][lane] = ef[(size_t)e * EF + lane];
            __builtin_amdgcn_wave_barrier();   // same-wave LDS RAW; compiler inserts waitcnt
            pg = b2f(SRC[(size_t)sN * 128 + lane]) + b2f(DST[(size_t)dN * 128 + lane]);
            ps = b2f(SRC[(size_t)sN * 128 + 64 + lane]) + b2f(DST[(size_t)dN * 128 + 64 + lane]);
#pragma unroll
            for (int k4 = 0; k4 < 40; k4 += 4) {
                float4 ev = *(const float4*)&erow[wid][k4];
                pg += ev.x * wg[k4] + ev.y * wg[k4 + 1] + ev.z * wg[k4 + 2] + ev.w * wg[k4 + 3];
                ps += ev.x * wsc[k4] + ev.y * wsc[k4 + 1] + ev.z * wsc[k4 + 2] + ev.w * wsc[k4 + 3];
            }
            {
                float ev = erow[wid][40];
                pg += ev * wg[40]; ps += ev * wsc[40];
            }
            bf16 gbit = f2b(pg), sbit = f2b(ps);
            pg = b2f(gbit); ps = b2f(sbit);   // keep stats consistent with stored precision
            if (MODE == 0) {
                PRE[(size_t)e * 128 + lane] = gbit;
                PRE[(size_t)e * 128 + 64 + lane] = sbit;
            }
            if (MODE == 0 || MODE == 2) { a0 += pg; a1 += pg * pg; a2 += ps; a3 += ps * ps; }
        } else {
            pg = b2f(PRE[(size_t)e * 128 + lane]);
            ps = b2f(PRE[(size_t)e * 128 + 64 + lane]);
        }
        if (MODE == 1 || MODE == 3) {
            float yg = scg * pg + shg;
            float ys = scs * ps + shs;
            float gate = 1.f / (1.f + expf(-yg));
            float scr = softplusf(ys);
            atomicAdd(&upd[(size_t)dN * D + lane], gate * scr);
        }
    }
    if (MODE == 0 || MODE == 2) {
        red[wid][0][lane] = a0; red[wid][1][lane] = a1; red[wid][2][lane] = a2; red[wid][3][lane] = a3;
        __syncthreads();
        if (tid < 64) {
#pragma unroll
            for (int t = 0; t < 4; t++) {
                float v = red[0][t][lane] + red[1][t][lane] + red[2][t][lane] + red[3][t][lane];
                atomicAdd(&stats[t * 64 + lane], v);
            }
        }
    }
}

// ---------------- column stats of upd
__global__ __launch_bounds__(256) void k_colstats(const float* __restrict__ x, float* __restrict__ stats, int N) {
    int tid = threadIdx.x, lane = tid & 63, wid = tid >> 6;
    __shared__ float red[4][2][64];
    float s = 0, q = 0;
    int gw = blockIdx.x * 4 + wid, nw = gridDim.x * 4;
    for (int r = gw; r < N; r += nw) {
        float v = x[(size_t)r * D + lane];
        s += v; q += v * v;
    }
    red[wid][0][lane] = s; red[wid][1][lane] = q;
    __syncthreads();
    if (tid < 64) {
        float a = red[0][0][lane] + red[1][0][lane] + red[2][0][lane] + red[3][0][lane];
        float b = red[0][1][lane] + red[1][1][lane] + red[2][1][lane] + red[3][1][lane];
        atomicAdd(&stats[lane], a);
        atomicAdd(&stats[64 + lane], b);
    }
}

// ---------------- h = softplus(BN(upd) + h)
__global__ void k_updapply(const float* __restrict__ upd, const float* __restrict__ stats,
                           const float* __restrict__ g, const float* __restrict__ beta,
                           float* __restrict__ h, int N, float invn) {
    int idx = blockIdx.x * blockDim.x + threadIdx.x;
    int total = N * D / 4;
    if (idx >= total) return;
    int c0 = (idx * 4) & 63;
    float4 u = ((const float4*)upd)[idx];
    float4 hh = ((const float4*)h)[idx];
    float uv[4] = {u.x, u.y, u.z, u.w}, hv[4] = {hh.x, hh.y, hh.z, hh.w}, o[4];
#pragma unroll
    for (int t = 0; t < 4; t++) {
        int c = c0 + t;
        float m = stats[c] * invn, v = stats[64 + c] * invn - m * m;
        float sc = g[c] * rsqrtf(fmaxf(v, 0.f) + EPS);
        float sh = beta[c] - m * sc;
        o[t] = softplusf(sc * uv[t] + sh + hv[t]);
    }
    ((float4*)h)[idx] = make_float4(o[0], o[1], o[2], o[3]);
}

// ---------------- segment-sum pool: batch is SORTED -> contiguous ranges per wave,
// register accumulation, one atomic per segment transition
__global__ __launch_bounds__(256) void k_pool(const float* __restrict__ h, const int* __restrict__ batch,
                                              float* __restrict__ pool, float* __restrict__ cnt, int N) {
    int tid = threadIdx.x, lane = tid & 63, wid = tid >> 6;
    int w = blockIdx.x * 4 + wid, nw = gridDim.x * 4;
    int chunk = (N + nw - 1) / nw;
    int r0 = w * chunk, r1 = min(N, r0 + chunk);
    if (r0 >= r1) return;
    int cur = batch[r0];
    float acc = 0.f, c = 0.f;
    for (int r = r0; r < r1; r++) {
        int b = batch[r];
        if (b != cur) {
            atomicAdd(&pool[(size_t)cur * D + lane], acc);
            if (lane == 0) atomicAdd(&cnt[cur], c);
            acc = 0.f; c = 0.f; cur = b;
        }
        acc += h[(size_t)r * D + lane];
        c += 1.f;
    }
    atomicAdd(&pool[(size_t)cur * D + lane], acc);
    if (lane == 0) atomicAdd(&cnt[cur], c);
}

// ---------------- fc: Y[g][j] = vt[g] . fcW[:,j] + fcb[j]; accumulate col stats
__global__ __launch_bounds__(128) void k_fc(const float* __restrict__ pool, const float* __restrict__ cnt,
                                            const float* __restrict__ fcW, const float* __restrict__ fcb,
                                            float* __restrict__ Y, float* __restrict__ ystats) {
    int g = blockIdx.x;
    int j = threadIdx.x;
    __shared__ float vt[FCW];
    {
        float s, c;
        if (j < 64) { s = pool[(size_t)g * D + j]; c = cnt[g]; }
        else { s = pool[4096 + (size_t)g * D + (j - 64)]; c = cnt[64 + g]; }
        vt[j] = s / fmaxf(c, 1.0f);
    }
    __syncthreads();
    float acc = fcb[j];
#pragma unroll
    for (int k4 = 0; k4 < FCW; k4 += 4) {
        float4 v = *(const float4*)&vt[k4];
        acc += v.x * fcW[(k4 + 0) * FCW + j] + v.y * fcW[(k4 + 1) * FCW + j] +
               v.z * fcW[(k4 + 2) * FCW + j] + v.w * fcW[(k4 + 3) * FCW + j];
    }
    Y[(size_t)g * FCW + j] = acc;
    atomicAdd(&ystats[j], acc);
    atomicAdd(&ystats[128 + j], acc * acc);
}

// ---------------- head: BN over 64 rows + SiLU + pred matvec → out[64] f32
__global__ __launch_bounds__(128) void k_head(const float* __restrict__ Y, const float* __restrict__ ystats,
                                              const float* __restrict__ fg, const float* __restrict__ fb,
                                              const float* __restrict__ pW, const float* __restrict__ pb,
                                              float* __restrict__ out) {
    int j = threadIdx.x;
    __shared__ float ys[NG][FCW + 1];
    __shared__ float pw[FCW];
    float invn = 1.0f / (float)NG;
    float m = ystats[j] * invn, v = ystats[128 + j] * invn - m * m;
    float sc = fg[j] * rsqrtf(fmaxf(v, 0.f) + EPS);
    float sh = fb[j] - m * sc;
    for (int g = 0; g < NG; g++) {
        float y = sc * Y[(size_t)g * FCW + j] + sh;
        ys[g][j] = y / (1.f + expf(-y));
    }
    pw[j] = pW[j];
    __syncthreads();
    if (j < NG) {
        float acc = pb[0];
        for (int k = 0; k < FCW; k++) acc += ys[j][k] * pw[k];
        out[j] = acc;
    }
}

// ---------------- workspace layout (bytes)
static const size_t OFF_EMBSTATS = 0;          // [2][128] f32
static const size_t OFF_EDGESTATS = 1024;      // [6][256] f32
static const size_t OFF_UPDSTATS = 7168;       // [6][128] f32
static const size_t OFF_POOL = 10240;          // [2][4096] f32
static const size_t OFF_CNT = 43008;           // [2][64] f32
static const size_t OFF_YSTATS = 43520;        // [256] f32
static const size_t STATS_BYTES = 44544;
static const size_t OFF_H = 65536;                         // 30000*64*4
static const size_t OFF_PRE = OFF_H + 7680000;             // emb preact f32
static const size_t OFF_UPD = OFF_PRE + 7680000;           // f32
static const size_t OFF_SRCTAB = OFF_UPD + 7680000;        // bf16 [30000][128]
static const size_t OFF_DSTTAB = OFF_SRCTAB + 7680000;
static const size_t OFF_Y = OFF_DSTTAB + 7680000;          // [64][128] f32
static const size_t OFF_EPRE = OFF_Y + 32768;              // bf16 [360000][128]
static const size_t NEED_STORE = OFF_EPRE + (size_t)NEDGE * 128 * 2;

extern "C" void kernel_launch(void* const* d_in, const int* in_sizes, int n_in,
                              void* d_out, int out_size, void* d_ws, size_t ws_size,
                              hipStream_t stream) {
    char* ws = (char*)d_ws;
    hipMemsetAsync(d_ws, 0, STATS_BYTES, stream);
    bool store = (ws_size >= NEED_STORE);

    float* h = (float*)(ws + OFF_H);
    float* pre = (float*)(ws + OFF_PRE);
    float* upd = (float*)(ws + OFF_UPD);
    bf16* SRCT = (bf16*)(ws + OFF_SRCTAB);
    bf16* DSTT = (bf16*)(ws + OFF_DSTTAB);
    bf16* EPRE = (bf16*)(ws + OFF_EPRE);

    for (int br = 0; br < 2; br++) {
        const float* vf = (const float*)d_in[br ? 2 : 0];
        const float* ef = (const float*)d_in[br ? 3 : 1];
        const int* srci = (const int*)d_in[br ? 7 : 4];
        const int* dsti = (const int*)d_in[br ? 8 : 5];
        const int* bat = (const int*)d_in[br ? 9 : 6];
        const float* embW = (const float*)d_in[br ? 14 : 10];
        const float* embB = (const float*)d_in[br ? 15 : 11];
        const float* embG = (const float*)d_in[br ? 16 : 12];
        const float* embBe = (const float*)d_in[br ? 17 : 13];
        const float* convW = (const float*)d_in[br ? 24 : 18];
        const float* convG = (const float*)d_in[br ? 26 : 20];
        const float* convBe = (const float*)d_in[br ? 27 : 21];
        const float* convNG = (const float*)d_in[br ? 28 : 22];
        const float* convNB = (const float*)d_in[br ? 29 : 23];

        float* embstats = (float*)(ws + OFF_EMBSTATS) + br * 128;
        float* poolp = (float*)(ws + OFF_POOL) + br * 4096;
        float* cntp = (float*)(ws + OFF_CNT) + br * 64;

        k_emb_mm<<<(NNODE + EMB_RPB - 1) / EMB_RPB, 256, 0, stream>>>(vf, embW, embB, pre, embstats, NNODE);
        k_bnsilu<<<NNODE * D / 4 / 256, 256, 0, stream>>>(pre, embstats, embG, embBe, h, NNODE, 1.0f / NNODE);

        for (int i = 0; i < LAY; i++) {
            const float* Wc = convW + (size_t)i * 2 * 169 * 64;
            float* estats = (float*)(ws + OFF_EDGESTATS) + (br * 3 + i) * 256;
            float* ustats = (float*)(ws + OFF_UPDSTATS) + (br * 3 + i) * 128;
            const float* gg = convG + (i * 2 + 0) * 64;
            const float* gb = convBe + (i * 2 + 0) * 64;
            const float* sg = convG + (i * 2 + 1) * 64;
            const float* sb = convBe + (i * 2 + 1) * 64;

            k_nodeproj<<<(NNODE + NP_RPB - 1) / NP_RPB, 256, 0, stream>>>(h, Wc, SRCT, DSTT, NNODE);
            if (store) {
                k_edge<0><<<768, 256, 0, stream>>>(srci, dsti, ef, Wc, SRCT, DSTT, EPRE, estats, gg, gb, sg, sb, upd, NEDGE, NNODE);
                k_edge<1><<<768, 256, 0, stream>>>(srci, dsti, ef, Wc, SRCT, DSTT, EPRE, estats, gg, gb, sg, sb, upd, NEDGE, NNODE);
            } else {
                k_edge<2><<<768, 256, 0, stream>>>(srci, dsti, ef, Wc, SRCT, DSTT, EPRE, estats, gg, gb, sg, sb, upd, NEDGE, NNODE);
                k_edge<3><<<768, 256, 0, stream>>>(srci, dsti, ef, Wc, SRCT, DSTT, EPRE, estats, gg, gb, sg, sb, upd, NEDGE, NNODE);
            }
            k_colstats<<<256, 256, 0, stream>>>(upd, ustats, NNODE);
            k_updapply<<<NNODE * D / 4 / 256, 256, 0, stream>>>(upd, ustats, convNG + i * 64, convNB + i * 64, h, NNODE, 1.0f / NNODE);
        }
        k_pool<<<128, 256, 0, stream>>>(h, bat, poolp, cntp, NNODE);
    }

    float* poolall = (float*)(ws + OFF_POOL);
    float* cntall = (float*)(ws + OFF_CNT);
    float* Y = (float*)(ws + OFF_Y);
    float* ystats = (float*)(ws + OFF_YSTATS);
    k_fc<<<64, 128, 0, stream>>>(poolall, cntall, (const float*)d_in[30], (const float*)d_in[31], Y, ystats);
    k_head<<<1, 128, 0, stream>>>(Y, ystats, (const float*)d_in[32], (const float*)d_in[33],
                                  (const float*)d_in[34], (const float*)d_in[35], (float*)d_out);
}

// Round 4
// 2008.051 us; speedup vs baseline: 1.3523x; 1.0758x over previous
//
#include <hip/hip_runtime.h>
#include <cstddef>

#define EPS 1e-5f
#define NNODE 30000
#define NEDGE 360000
#define NFEAT 92
#define EF 41
#define D 64
#define LAY 3
#define FCW 128
#define NG 64

typedef unsigned short bf16;

__device__ __forceinline__ float b2f(bf16 u) { return __uint_as_float(((unsigned)u) << 16); }
__device__ __forceinline__ bf16 f2b(float f) {
    unsigned u = __float_as_uint(f);
    unsigned r = (u + 0x7FFFu + ((u >> 16) & 1u)) >> 16;
    return (bf16)r;
}
__device__ __forceinline__ float softplusf(float x) {
    return fmaxf(x, 0.0f) + log1pf(expf(-fabsf(x)));
}

// ---------------- embedding matmul: pre = X[N,92] @ W[92,64] + b, accumulate col stats
#define EMB_RPB 64
__global__ __launch_bounds__(256) void k_emb_mm(const float* __restrict__ X, const float* __restrict__ W,
                                                const float* __restrict__ bias, float* __restrict__ pre,
                                                float* __restrict__ stats, int N) {
    __shared__ float xs[EMB_RPB][NFEAT];   // 23.5 KB; row stride 368B = 16B aligned
    __shared__ float red[4][2][64];
    int tid = threadIdx.x;
    int lane = tid & 63, wid = tid >> 6;
    int r0 = blockIdx.x * EMB_RPB;
    float w[NFEAT];
#pragma unroll
    for (int k = 0; k < NFEAT; k++) w[k] = W[k * D + lane];
    float bcol = bias[lane];
    for (int i = tid; i < EMB_RPB * (NFEAT / 4); i += 256) {
        int rr = i / (NFEAT / 4), kk = i - rr * (NFEAT / 4);
        int r = r0 + rr;
        float4 v = (r < N) ? ((const float4*)(X + (size_t)r * NFEAT))[kk] : make_float4(0, 0, 0, 0);
        *(float4*)&xs[rr][kk * 4] = v;
    }
    __syncthreads();
    float s0 = 0.f, s1 = 0.f;
    for (int rr = wid * 16; rr < wid * 16 + 16; rr++) {
        int r = r0 + rr;
        if (r >= N) break;
        float acc = bcol;
#pragma unroll
        for (int k4 = 0; k4 < NFEAT; k4 += 4) {
            float4 xv = *(const float4*)&xs[rr][k4];
            acc += xv.x * w[k4] + xv.y * w[k4 + 1] + xv.z * w[k4 + 2] + xv.w * w[k4 + 3];
        }
        pre[r * D + lane] = acc;
        s0 += acc; s1 += acc * acc;
    }
    red[wid][0][lane] = s0; red[wid][1][lane] = s1;
    __syncthreads();
    if (tid < 64) {
        float a = red[0][0][lane] + red[1][0][lane] + red[2][0][lane] + red[3][0][lane];
        float b = red[0][1][lane] + red[1][1][lane] + red[2][1][lane] + red[3][1][lane];
        atomicAdd(&stats[lane], a);
        atomicAdd(&stats[64 + lane], b);
    }
}

// ---------------- BN + SiLU elementwise (stats finalized inline)
__global__ void k_bnsilu(const float* __restrict__ pre, const float* __restrict__ stats,
                         const float* __restrict__ g, const float* __restrict__ beta,
                         float* __restrict__ h, int N, float invn) {
    int idx = blockIdx.x * blockDim.x + threadIdx.x;
    int total = N * D / 4;
    if (idx >= total) return;
    int c0 = (idx * 4) & 63;
    float4 p = ((const float4*)pre)[idx];
    float pv[4] = {p.x, p.y, p.z, p.w}, o[4];
#pragma unroll
    for (int t = 0; t < 4; t++) {
        int c = c0 + t;
        float m = stats[c] * invn;
        float v = stats[64 + c] * invn - m * m;
        float sc = g[c] * rsqrtf(fmaxf(v, 0.f) + EPS);
        float sh = beta[c] - m * sc;
        float y = sc * pv[t] + sh;
        o[t] = y / (1.f + expf(-y));
    }
    ((float4*)h)[idx] = make_float4(o[0], o[1], o[2], o[3]);
}

// ---------------- node projections: SRC[n]=[h@Wg[0:64] | h@Ws[0:64]], DST=[h@Wg[64:128] | h@Ws[64:128]]
#define NP_RPB 64
__global__ __launch_bounds__(256) void k_nodeproj(const float* __restrict__ h, const float* __restrict__ Wc,
                                                  bf16* __restrict__ SRC, bf16* __restrict__ DST, int N) {
    __shared__ float hs[NP_RPB][D];   // 16 KB
    int tid = threadIdx.x;
    int j = tid & 63;
    int mat = tid >> 6;          // 0: src-gate 1: src-scr 2: dst-gate 3: dst-scr
    int jj = mat & 1;
    int roff = (mat >> 1) * 64;
    const float* Wb = Wc + ((size_t)jj * 169 + roff) * 64 + j;
    float w[D];
#pragma unroll
    for (int k = 0; k < D; k++) w[k] = Wb[k * 64];
    int r0 = blockIdx.x * NP_RPB;
    for (int i = tid; i < NP_RPB * D / 4; i += 256) {
        int rr = i >> 4, kk = (i & 15);
        int r = r0 + rr;
        float4 v = (r < N) ? ((const float4*)(h + (size_t)r * D))[kk] : make_float4(0, 0, 0, 0);
        *(float4*)&hs[rr][kk * 4] = v;
    }
    __syncthreads();
    bf16* out = (mat < 2) ? SRC : DST;
    int coff = jj * 64 + j;
    int rmax = min(NP_RPB, N - r0);
    for (int rr = 0; rr < rmax; rr++) {
        float acc = 0.f;
#pragma unroll
        for (int k4 = 0; k4 < D; k4 += 4) {
            float4 xv = *(const float4*)&hs[rr][k4];
            acc += xv.x * w[k4] + xv.y * w[k4 + 1] + xv.z * w[k4 + 2] + xv.w * w[k4 + 3];
        }
        out[(size_t)(r0 + rr) * 128 + coff] = f2b(acc);
    }
}

// ---------------- edge pass, 2 edges per wave-iteration.
// MODE: 0 stats+store, 1 load+apply, 2 stats only, 3 recompute+apply
template <int MODE>
__global__ __launch_bounds__(256) void k_edge(const int* __restrict__ src, const int* __restrict__ dst,
                                              const float* __restrict__ ef, const float* __restrict__ Wc,
                                              const bf16* __restrict__ SRC, const bf16* __restrict__ DST,
                                              bf16* __restrict__ PRE, float* __restrict__ stats,
                                              const float* __restrict__ gg, const float* __restrict__ gb,
                                              const float* __restrict__ sg, const float* __restrict__ sb,
                                              float* __restrict__ upd, int E, int N) {
    int tid = threadIdx.x, lane = tid & 63;
    int wid = __builtin_amdgcn_readfirstlane(tid >> 6);   // provably wave-uniform -> scalar loads
    if (MODE == 0 || MODE == 2) {    // fuse: zero upd for the subsequent apply pass
        int gsz = gridDim.x * 256;
        for (int i = blockIdx.x * 256 + tid; i < N * D; i += gsz) upd[i] = 0.f;
    }
    float wg[EF], wsc[EF];
    if (MODE != 1) {
#pragma unroll
        for (int k = 0; k < EF; k++) {
            wg[k] = Wc[(128 + k) * 64 + lane];
            wsc[k] = Wc[(169 + 128 + k) * 64 + lane];
        }
    }
    float scg = 0, shg = 0, scs = 0, shs = 0;
    if (MODE == 1 || MODE == 3) {
        float invE = 1.0f / (float)E;
        float m = stats[lane] * invE;
        float v = stats[64 + lane] * invE - m * m;
        scg = gg[lane] * rsqrtf(fmaxf(v, 0.f) + EPS);
        shg = gb[lane] - m * scg;
        m = stats[128 + lane] * invE;
        v = stats[192 + lane] * invE - m * m;
        scs = sg[lane] * rsqrtf(fmaxf(v, 0.f) + EPS);
        shs = sb[lane] - m * scs;
    }
    __shared__ float erow[4][2][44];
    __shared__ float red[4][4][64];
    float a0 = 0, a1 = 0, a2 = 0, a3 = 0;
    int gw = blockIdx.x * 4 + wid, nw = gridDim.x * 4;
    int P = E >> 1;                       // E is even (360000)
    for (int p = gw; p < P; p += nw) {
        int e0 = 2 * p, e1 = e0 + 1;
        int s0i = src[e0], d0i = dst[e0];
        int s1i = src[e1], d1i = dst[e1];
        float pg0, ps0, pg1, ps1;
        if (MODE != 1) {
            if (lane < EF) {
                erow[wid][0][lane] = ef[(size_t)e0 * EF + lane];
                erow[wid][1][lane] = ef[(size_t)e1 * EF + lane];
            }
            __builtin_amdgcn_wave_barrier();   // same-wave LDS RAW; compiler inserts waitcnt
            pg0 = b2f(SRC[(size_t)s0i * 128 + lane]) + b2f(DST[(size_t)d0i * 128 + lane]);
            ps0 = b2f(SRC[(size_t)s0i * 128 + 64 + lane]) + b2f(DST[(size_t)d0i * 128 + 64 + lane]);
            pg1 = b2f(SRC[(size_t)s1i * 128 + lane]) + b2f(DST[(size_t)d1i * 128 + lane]);
            ps1 = b2f(SRC[(size_t)s1i * 128 + 64 + lane]) + b2f(DST[(size_t)d1i * 128 + 64 + lane]);
            float qg0 = 0, qs0 = 0, qg1 = 0, qs1 = 0;   // second accumulator set -> 8 indep chains
#pragma unroll
            for (int k4 = 0; k4 < 40; k4 += 4) {
                float4 u0 = *(const float4*)&erow[wid][0][k4];
                float4 u1 = *(const float4*)&erow[wid][1][k4];
                if (((k4 >> 2) & 1) == 0) {
                    pg0 += u0.x * wg[k4] + u0.y * wg[k4 + 1] + u0.z * wg[k4 + 2] + u0.w * wg[k4 + 3];
                    ps0 += u0.x * wsc[k4] + u0.y * wsc[k4 + 1] + u0.z * wsc[k4 + 2] + u0.w * wsc[k4 + 3];
                    pg1 += u1.x * wg[k4] + u1.y * wg[k4 + 1] + u1.z * wg[k4 + 2] + u1.w * wg[k4 + 3];
                    ps1 += u1.x * wsc[k4] + u1.y * wsc[k4 + 1] + u1.z * wsc[k4 + 2] + u1.w * wsc[k4 + 3];
                } else {
                    qg0 += u0.x * wg[k4] + u0.y * wg[k4 + 1] + u0.z * wg[k4 + 2] + u0.w * wg[k4 + 3];
                    qs0 += u0.x * wsc[k4] + u0.y * wsc[k4 + 1] + u0.z * wsc[k4 + 2] + u0.w * wsc[k4 + 3];
                    qg1 += u1.x * wg[k4] + u1.y * wg[k4 + 1] + u1.z * wg[k4 + 2] + u1.w * wg[k4 + 3];
                    qs1 += u1.x * wsc[k4] + u1.y * wsc[k4 + 1] + u1.z * wsc[k4 + 2] + u1.w * wsc[k4 + 3];
                }
            }
            {
                float ev0 = erow[wid][0][40], ev1 = erow[wid][1][40];
                qg0 += ev0 * wg[40]; qs0 += ev0 * wsc[40];
                qg1 += ev1 * wg[40]; qs1 += ev1 * wsc[40];
            }
            pg0 += qg0; ps0 += qs0; pg1 += qg1; ps1 += qs1;
            bf16 g0b = f2b(pg0), s0b = f2b(ps0), g1b = f2b(pg1), s1b = f2b(ps1);
            pg0 = b2f(g0b); ps0 = b2f(s0b); pg1 = b2f(g1b); ps1 = b2f(s1b);
            if (MODE == 0) {
                PRE[(size_t)e0 * 128 + lane] = g0b;
                PRE[(size_t)e0 * 128 + 64 + lane] = s0b;
                PRE[(size_t)e1 * 128 + lane] = g1b;
                PRE[(size_t)e1 * 128 + 64 + lane] = s1b;
            }
            if (MODE == 0 || MODE == 2) {
                a0 += pg0 + pg1; a1 += pg0 * pg0 + pg1 * pg1;
                a2 += ps0 + ps1; a3 += ps0 * ps0 + ps1 * ps1;
            }
        } else {
            pg0 = b2f(PRE[(size_t)e0 * 128 + lane]);
            ps0 = b2f(PRE[(size_t)e0 * 128 + 64 + lane]);
            pg1 = b2f(PRE[(size_t)e1 * 128 + lane]);
            ps1 = b2f(PRE[(size_t)e1 * 128 + 64 + lane]);
        }
        if (MODE == 1 || MODE == 3) {
            float yg0 = scg * pg0 + shg, ys0 = scs * ps0 + shs;
            float yg1 = scg * pg1 + shg, ys1 = scs * ps1 + shs;
            float v0 = softplusf(ys0) / (1.f + expf(-yg0));
            float v1 = softplusf(ys1) / (1.f + expf(-yg1));
            atomicAdd(&upd[(size_t)d0i * D + lane], v0);
            atomicAdd(&upd[(size_t)d1i * D + lane], v1);
        }
    }
    if ((E & 1) && gw == 0) {     // safety tail (E is even in practice)
        int e = E - 1;
        int sN = src[e], dN = dst[e];
        float pg, ps;
        if (MODE != 1) {
            if (lane < EF) erow[wid][0][lane] = ef[(size_t)e * EF + lane];
            __builtin_amdgcn_wave_barrier();
            pg = b2f(SRC[(size_t)sN * 128 + lane]) + b2f(DST[(size_t)dN * 128 + lane]);
            ps = b2f(SRC[(size_t)sN * 128 + 64 + lane]) + b2f(DST[(size_t)dN * 128 + 64 + lane]);
            for (int k = 0; k < EF; k++) {
                float ev = erow[wid][0][k];
                pg += ev * wg[k]; ps += ev * wsc[k];
            }
            bf16 gbit = f2b(pg), sbit = f2b(ps);
            pg = b2f(gbit); ps = b2f(sbit);
            if (MODE == 0) {
                PRE[(size_t)e * 128 + lane] = gbit;
                PRE[(size_t)e * 128 + 64 + lane] = sbit;
            }
            if (MODE == 0 || MODE == 2) { a0 += pg; a1 += pg * pg; a2 += ps; a3 += ps * ps; }
        } else {
            pg = b2f(PRE[(size_t)e * 128 + lane]);
            ps = b2f(PRE[(size_t)e * 128 + 64 + lane]);
        }
        if (MODE == 1 || MODE == 3) {
            float yg = scg * pg + shg, ys = scs * ps + shs;
            atomicAdd(&upd[(size_t)dN * D + lane], softplusf(ys) / (1.f + expf(-yg)));
        }
    }
    if (MODE == 0 || MODE == 2) {
        red[wid][0][lane] = a0; red[wid][1][lane] = a1; red[wid][2][lane] = a2; red[wid][3][lane] = a3;
        __syncthreads();
        if (tid < 64) {
#pragma unroll
            for (int t = 0; t < 4; t++) {
                float v = red[0][t][lane] + red[1][t][lane] + red[2][t][lane] + red[3][t][lane];
                atomicAdd(&stats[t * 64 + lane], v);
            }
        }
    }
}

// ---------------- column stats of upd
__global__ __launch_bounds__(256) void k_colstats(const float* __restrict__ x, float* __restrict__ stats, int N) {
    int tid = threadIdx.x, lane = tid & 63, wid = tid >> 6;
    __shared__ float red[4][2][64];
    float s = 0, q = 0;
    int gw = blockIdx.x * 4 + wid, nw = gridDim.x * 4;
    for (int r = gw; r < N; r += nw) {
        float v = x[(size_t)r * D + lane];
        s += v; q += v * v;
    }
    red[wid][0][lane] = s; red[wid][1][lane] = q;
    __syncthreads();
    if (tid < 64) {
        float a = red[0][0][lane] + red[1][0][lane] + red[2][0][lane] + red[3][0][lane];
        float b = red[0][1][lane] + red[1][1][lane] + red[2][1][lane] + red[3][1][lane];
        atomicAdd(&stats[lane], a);
        atomicAdd(&stats[64 + lane], b);
    }
}

// ---------------- h = softplus(BN(upd) + h)
__global__ void k_updapply(const float* __restrict__ upd, const float* __restrict__ stats,
                           const float* __restrict__ g, const float* __restrict__ beta,
                           float* __restrict__ h, int N, float invn) {
    int idx = blockIdx.x * blockDim.x + threadIdx.x;
    int total = N * D / 4;
    if (idx >= total) return;
    int c0 = (idx * 4) & 63;
    float4 u = ((const float4*)upd)[idx];
    float4 hh = ((const float4*)h)[idx];
    float uv[4] = {u.x, u.y, u.z, u.w}, hv[4] = {hh.x, hh.y, hh.z, hh.w}, o[4];
#pragma unroll
    for (int t = 0; t < 4; t++) {
        int c = c0 + t;
        float m = stats[c] * invn, v = stats[64 + c] * invn - m * m;
        float sc = g[c] * rsqrtf(fmaxf(v, 0.f) + EPS);
        float sh = beta[c] - m * sc;
        o[t] = softplusf(sc * uv[t] + sh + hv[t]);
    }
    ((float4*)h)[idx] = make_float4(o[0], o[1], o[2], o[3]);
}

// ---------------- segment-sum pool: batch is SORTED -> contiguous ranges per wave,
// register accumulation, one atomic per segment transition
__global__ __launch_bounds__(256) void k_pool(const float* __restrict__ h, const int* __restrict__ batch,
                                              float* __restrict__ pool, float* __restrict__ cnt, int N) {
    int tid = threadIdx.x, lane = tid & 63, wid = tid >> 6;
    int w = blockIdx.x * 4 + wid, nw = gridDim.x * 4;
    int chunk = (N + nw - 1) / nw;
    int r0 = w * chunk, r1 = min(N, r0 + chunk);
    if (r0 >= r1) return;
    int cur = batch[r0];
    float acc = 0.f, c = 0.f;
    for (int r = r0; r < r1; r++) {
        int b = batch[r];
        if (b != cur) {
            atomicAdd(&pool[(size_t)cur * D + lane], acc);
            if (lane == 0) atomicAdd(&cnt[cur], c);
            acc = 0.f; c = 0.f; cur = b;
        }
        acc += h[(size_t)r * D + lane];
        c += 1.f;
    }
    atomicAdd(&pool[(size_t)cur * D + lane], acc);
    if (lane == 0) atomicAdd(&cnt[cur], c);
}

// ---------------- fc: Y[g][j] = vt[g] . fcW[:,j] + fcb[j]; accumulate col stats
__global__ __launch_bounds__(128) void k_fc(const float* __restrict__ pool, const float* __restrict__ cnt,
                                            const float* __restrict__ fcW, const float* __restrict__ fcb,
                                            float* __restrict__ Y, float* __restrict__ ystats) {
    int g = blockIdx.x;
    int j = threadIdx.x;
    __shared__ float vt[FCW];
    {
        float s, c;
        if (j < 64) { s = pool[(size_t)g * D + j]; c = cnt[g]; }
        else { s = pool[4096 + (size_t)g * D + (j - 64)]; c = cnt[64 + g]; }
        vt[j] = s / fmaxf(c, 1.0f);
    }
    __syncthreads();
    float acc = fcb[j];
#pragma unroll
    for (int k4 = 0; k4 < FCW; k4 += 4) {
        float4 v = *(const float4*)&vt[k4];
        acc += v.x * fcW[(k4 + 0) * FCW + j] + v.y * fcW[(k4 + 1) * FCW + j] +
               v.z * fcW[(k4 + 2) * FCW + j] + v.w * fcW[(k4 + 3) * FCW + j];
    }
    Y[(size_t)g * FCW + j] = acc;
    atomicAdd(&ystats[j], acc);
    atomicAdd(&ystats[128 + j], acc * acc);
}

// ---------------- head: BN over 64 rows + SiLU + pred matvec → out[64] f32
__global__ __launch_bounds__(128) void k_head(const float* __restrict__ Y, const float* __restrict__ ystats,
                                              const float* __restrict__ fg, const float* __restrict__ fb,
                                              const float* __restrict__ pW, const float* __restrict__ pb,
                                              float* __restrict__ out) {
    int j = threadIdx.x;
    __shared__ float ys[NG][FCW + 1];
    __shared__ float pw[FCW];
    float invn = 1.0f / (float)NG;
    float m = ystats[j] * invn, v = ystats[128 + j] * invn - m * m;
    float sc = fg[j] * rsqrtf(fmaxf(v, 0.f) + EPS);
    float sh = fb[j] - m * sc;
    for (int g = 0; g < NG; g++) {
        float y = sc * Y[(size_t)g * FCW + j] + sh;
        ys[g][j] = y / (1.f + expf(-y));
    }
    pw[j] = pW[j];
    __syncthreads();
    if (j < NG) {
        float acc = pb[0];
        for (int k = 0; k < FCW; k++) acc += ys[j][k] * pw[k];
        out[j] = acc;
    }
}

// ---------------- workspace layout (bytes)
static const size_t OFF_EMBSTATS = 0;          // [2][128] f32
static const size_t OFF_EDGESTATS = 1024;      // [6][256] f32
static const size_t OFF_UPDSTATS = 7168;       // [6][128] f32
static const size_t OFF_POOL = 10240;          // [2][4096] f32
static const size_t OFF_CNT = 43008;           // [2][64] f32
static const size_t OFF_YSTATS = 43520;        // [256] f32
static const size_t STATS_BYTES = 44544;
static const size_t OFF_H = 65536;                         // 30000*64*4
static const size_t OFF_PRE = OFF_H + 7680000;             // emb preact f32
static const size_t OFF_UPD = OFF_PRE + 7680000;           // f32
static const size_t OFF_SRCTAB = OFF_UPD + 7680000;        // bf16 [30000][128]
static const size_t OFF_DSTTAB = OFF_SRCTAB + 7680000;
static const size_t OFF_Y = OFF_DSTTAB + 7680000;          // [64][128] f32
static const size_t OFF_EPRE = OFF_Y + 32768;              // bf16 [360000][128]
static const size_t NEED_STORE = OFF_EPRE + (size_t)NEDGE * 128 * 2;

extern "C" void kernel_launch(void* const* d_in, const int* in_sizes, int n_in,
                              void* d_out, int out_size, void* d_ws, size_t ws_size,
                              hipStream_t stream) {
    char* ws = (char*)d_ws;
    hipMemsetAsync(d_ws, 0, STATS_BYTES, stream);
    bool store = (ws_size >= NEED_STORE);

    float* h = (float*)(ws + OFF_H);
    float* pre = (float*)(ws + OFF_PRE);
    float* upd = (float*)(ws + OFF_UPD);
    bf16* SRCT = (bf16*)(ws + OFF_SRCTAB);
    bf16* DSTT = (bf16*)(ws + OFF_DSTTAB);
    bf16* EPRE = (bf16*)(ws + OFF_EPRE);

    for (int br = 0; br < 2; br++) {
        const float* vf = (const float*)d_in[br ? 2 : 0];
        const float* ef = (const float*)d_in[br ? 3 : 1];
        const int* srci = (const int*)d_in[br ? 7 : 4];
        const int* dsti = (const int*)d_in[br ? 8 : 5];
        const int* bat = (const int*)d_in[br ? 9 : 6];
        const float* embW = (const float*)d_in[br ? 14 : 10];
        const float* embB = (const float*)d_in[br ? 15 : 11];
        const float* embG = (const float*)d_in[br ? 16 : 12];
        const float* embBe = (const float*)d_in[br ? 17 : 13];
        const float* convW = (const float*)d_in[br ? 24 : 18];
        const float* convG = (const float*)d_in[br ? 26 : 20];
        const float* convBe = (const float*)d_in[br ? 27 : 21];
        const float* convNG = (const float*)d_in[br ? 28 : 22];
        const float* convNB = (const float*)d_in[br ? 29 : 23];

        float* embstats = (float*)(ws + OFF_EMBSTATS) + br * 128;
        float* poolp = (float*)(ws + OFF_POOL) + br * 4096;
        float* cntp = (float*)(ws + OFF_CNT) + br * 64;

        k_emb_mm<<<(NNODE + EMB_RPB - 1) / EMB_RPB, 256, 0, stream>>>(vf, embW, embB, pre, embstats, NNODE);
        k_bnsilu<<<NNODE * D / 4 / 256, 256, 0, stream>>>(pre, embstats, embG, embBe, h, NNODE, 1.0f / NNODE);

        for (int i = 0; i < LAY; i++) {
            const float* Wc = convW + (size_t)i * 2 * 169 * 64;
            float* estats = (float*)(ws + OFF_EDGESTATS) + (br * 3 + i) * 256;
            float* ustats = (float*)(ws + OFF_UPDSTATS) + (br * 3 + i) * 128;
            const float* gg = convG + (i * 2 + 0) * 64;
            const float* gb = convBe + (i * 2 + 0) * 64;
            const float* sg = convG + (i * 2 + 1) * 64;
            const float* sb = convBe + (i * 2 + 1) * 64;

            k_nodeproj<<<(NNODE + NP_RPB - 1) / NP_RPB, 256, 0, stream>>>(h, Wc, SRCT, DSTT, NNODE);
            if (store) {
                k_edge<0><<<2048, 256, 0, stream>>>(srci, dsti, ef, Wc, SRCT, DSTT, EPRE, estats, gg, gb, sg, sb, upd, NEDGE, NNODE);
                k_edge<1><<<2048, 256, 0, stream>>>(srci, dsti, ef, Wc, SRCT, DSTT, EPRE, estats, gg, gb, sg, sb, upd, NEDGE, NNODE);
            } else {
                k_edge<2><<<2048, 256, 0, stream>>>(srci, dsti, ef, Wc, SRCT, DSTT, EPRE, estats, gg, gb, sg, sb, upd, NEDGE, NNODE);
                k_edge<3><<<2048, 256, 0, stream>>>(srci, dsti, ef, Wc, SRCT, DSTT, EPRE, estats, gg, gb, sg, sb, upd, NEDGE, NNODE);
            }
            k_colstats<<<512, 256, 0, stream>>>(upd, ustats, NNODE);
            k_updapply<<<NNODE * D / 4 / 256, 256, 0, stream>>>(upd, ustats, convNG + i * 64, convNB + i * 64, h, NNODE, 1.0f / NNODE);
        }
        k_pool<<<128, 256, 0, stream>>>(h, bat, poolp, cntp, NNODE);
    }

    float* poolall = (float*)(ws + OFF_POOL);
    float* cntall = (float*)(ws + OFF_CNT);
    float* Y = (float*)(ws + OFF_Y);
    float* ystats = (float*)(ws + OFF_YSTATS);
    k_fc<<<64, 128, 0, stream>>>(poolall, cntall, (const float*)d_in[30], (const float*)d_in[31], Y, ystats);
    k_head<<<1, 128, 0, stream>>>(Y, ystats, (const float*)d_in[32], (const float*)d_in[33],
                                  (const float*)d_in[34], (const float*)d_in[35], (float*)d_out);
}